// Round 8
// baseline (237.090 us; speedup 1.0000x reference)
//
#include <hip/hip_runtime.h>
#include <hip/hip_fp16.h>

typedef _Float16 f16;
typedef _Float16 f16x8 __attribute__((ext_vector_type(8)));
typedef _Float16 f16x4 __attribute__((ext_vector_type(4)));
typedef float f32x4 __attribute__((ext_vector_type(4)));
typedef float f32x16 __attribute__((ext_vector_type(16)));

#define GLB(p) ((const __attribute__((address_space(1))) void*)(p))
#define LDSP(p) ((__attribute__((address_space(3))) void*)(p))

__device__ __forceinline__ void gload16(const void* g, void* l) {
  __builtin_amdgcn_global_load_lds(GLB(g), LDSP(l), 16, 0, 0);
}

#define VMW(n) asm volatile("s_waitcnt vmcnt(" #n ")" ::: "memory")
__device__ __forceinline__ void barrier_fenced() {
  asm volatile("" ::: "memory");
  __builtin_amdgcn_s_barrier();
  asm volatile("" ::: "memory");
}

// ---------------- prep (merged): x->f16 + weight permute-transpose ----------------
__global__ __launch_bounds__(256) void prep_all(
    const float* __restrict__ x, const float* __restrict__ Wq,
    const float* __restrict__ Wk, const float* __restrict__ Wv,
    const float* __restrict__ Wo, const float* __restrict__ bq,
    const float* __restrict__ bk, const float* __restrict__ bv,
    f16* __restrict__ xb, f16* __restrict__ WqT, f16* __restrict__ WkT,
    f16* __restrict__ WvT, f16* __restrict__ WoT, float* __restrict__ bqp,
    float* __restrict__ bkp, float* __restrict__ bvp) {
  int g = blockIdx.x * 256 + threadIdx.x;  // 0..1048575
  {
    int i = g * 4;
    float4 v = *(const float4*)(x + i);
    f16x4 o = {(f16)v.x, (f16)v.y, (f16)v.z, (f16)v.w};
    *(f16x4*)(xb + i) = o;
  }
  if (g < 524288) {
    int i = g;
    {
      int np = i >> 8, c = i & 255;
      int src = c * 2048 + (np & 255) * 8 + (np >> 8);
      WqT[i] = (f16)Wq[src];
      WkT[i] = (f16)Wk[src];
      WvT[i] = (f16)Wv[src];
    }
    {
      int dm = i >> 11, np = i & 2047;
      WoT[i] = (f16)Wo[((np & 255) * 8 + (np >> 8)) * 256 + dm];
    }
    if (i < 2048) {
      int src = (i & 255) * 8 + (i >> 8);
      bqp[i] = bq[src];
      bkp[i] = bk[src];
      bvp[i] = bv[src];
    }
  }
}

// ------- merged 256x256-tile fp16 GEMM (QK-proj blocks 0..1023, V-proj 1024..1535) -------
// Body = round-7 gemm256 (2-phase/tile, 3-buf, counted VMW(4) once per tile).
// A(m,k) elem = (m>>8)*aq1 + (m&255)*256 + k ; B(n,k) elem = n*256 + k
// C(m,n) elem = (m>>8)*cp1 + (m&255)*256 + (n>>8)*cp3 + (n&255)  (f16)
__global__ __launch_bounds__(512, 2) void gemm_qkv(
    const f16* __restrict__ A0, const f16* __restrict__ B0,
    const float* __restrict__ bias0, f16* __restrict__ C0,
    const f16* __restrict__ A1, const f16* __restrict__ B1,
    const float* __restrict__ bias1, f16* __restrict__ C1) {
  __shared__ __align__(16) char smem[98304];
  const int tid = threadIdx.x;
  const int lane = tid & 63;
  const int wid = tid >> 6;
  const int l31 = lane & 31, lh = lane >> 5;
  const int wr = wid >> 2, wc = wid & 3;  // wave grid 2(M) x 4(N)

  const bool isV = blockIdx.x >= 1024;
  const f16* A = isV ? A1 : A0;
  const f16* B = isV ? B1 : B0;
  const float* bias = isV ? bias1 : bias0;
  f16* C = isV ? C1 : C0;
  const int NT = isV ? 64 : 16;
  const long cp1 = isV ? 65536L : 1048576L;
  const long cp3 = isV ? 524288L : 65536L;
  const int lbid = isV ? (blockIdx.x - 1024) : blockIdx.x;
  const int nwg = isV ? 512 : 1024;
  const int sw = (lbid & 7) * (nwg >> 3) + (lbid >> 3);  // XCD swizzle
  const int n0 = (sw % NT) * 256, m0 = (sw / NT) * 256;
  const int aq1 = 65536;

  auto stageA = [&](int buf, int kt) {
#pragma unroll
    for (int r = 0; r < 2; ++r) {
      int flat = r * 8192 + tid * 16;
      int row = flat >> 6;
      int kk = kt * 32 + (((flat ^ (((row >> 1) & 3) << 4)) & 63) >> 1);
      int m = m0 + row;
      gload16(A + (long)(m >> 8) * aq1 + (long)(m & 255) * 256 + kk,
              smem + buf * 16384 + flat);
    }
  };
  auto stageB = [&](int buf, int kt) {
#pragma unroll
    for (int r = 0; r < 2; ++r) {
      int flat = r * 8192 + tid * 16;
      int row = flat >> 6;
      int kk = kt * 32 + (((flat ^ (((row >> 1) & 3) << 4)) & 63) >> 1);
      gload16(B + (long)(n0 + row) * 256 + kk,
              smem + 49152 + buf * 16384 + flat);
    }
  };
  auto ldA = [&](int buf, int row, int kf) -> f16x8 {
    int cb = kf * 32 + lh * 16;
    return *(const f16x8*)(smem + buf * 16384 + row * 64 +
                           (cb ^ (((row >> 1) & 3) << 4)));
  };
  auto ldB = [&](int buf, int row, int kf) -> f16x8 {
    int cb = kf * 32 + lh * 16;
    return *(const f16x8*)(smem + 49152 + buf * 16384 + row * 64 +
                           (cb ^ (((row >> 1) & 3) << 4)));
  };

  f32x16 acc[4][2] = {};
  stageA(0, 0);
  stageB(0, 0);
  stageA(1, 1);
  stageB(1, 1);
  VMW(4);
  barrier_fenced();
#pragma unroll
  for (int t = 0; t < 8; ++t) {
    const int buf = t % 3;
    const int sb = (t + 2) % 3;
    f16x8 a[4], b[2];
#pragma unroll
    for (int mi = 0; mi < 4; ++mi) a[mi] = ldA(buf, wr * 128 + mi * 32 + l31, 0);
#pragma unroll
    for (int ni = 0; ni < 2; ++ni) b[ni] = ldB(buf, wc * 64 + ni * 32 + l31, 0);
    if (t < 6) stageA(sb, t + 2);
    barrier_fenced();
    __builtin_amdgcn_s_setprio(1);
#pragma unroll
    for (int mi = 0; mi < 4; ++mi)
#pragma unroll
      for (int ni = 0; ni < 2; ++ni)
        acc[mi][ni] = __builtin_amdgcn_mfma_f32_32x32x16_f16(a[mi], b[ni],
                                                             acc[mi][ni], 0, 0, 0);
    __builtin_amdgcn_s_setprio(0);
    barrier_fenced();
#pragma unroll
    for (int mi = 0; mi < 4; ++mi) a[mi] = ldA(buf, wr * 128 + mi * 32 + l31, 1);
#pragma unroll
    for (int ni = 0; ni < 2; ++ni) b[ni] = ldB(buf, wc * 64 + ni * 32 + l31, 1);
    if (t < 6) stageB(sb, t + 2);
    barrier_fenced();
    __builtin_amdgcn_s_setprio(1);
#pragma unroll
    for (int mi = 0; mi < 4; ++mi)
#pragma unroll
      for (int ni = 0; ni < 2; ++ni)
        acc[mi][ni] = __builtin_amdgcn_mfma_f32_32x32x16_f16(a[mi], b[ni],
                                                             acc[mi][ni], 0, 0, 0);
    __builtin_amdgcn_s_setprio(0);
    if (t < 6) {
      VMW(4);
    } else if (t == 6) {
      VMW(0);
    }
    barrier_fenced();
  }

  // epilogue: C/D layout col=lane&31, row=(reg&3)+8*(reg>>2)+4*(lane>>5)
#pragma unroll
  for (int mi = 0; mi < 4; ++mi)
#pragma unroll
    for (int ni = 0; ni < 2; ++ni)
#pragma unroll
      for (int reg = 0; reg < 16; ++reg) {
        int m = m0 + wr * 128 + mi * 32 + (reg & 3) + 8 * (reg >> 2) + 4 * lh;
        int n = n0 + wc * 64 + ni * 32 + l31;
        float v = acc[mi][ni][reg];
        v += isV ? bias[m] : bias[n];
        long off = (long)(m >> 8) * cp1 + (long)(m & 255) * 256 +
                   (long)(n >> 8) * cp3 + (n & 255);
        C[off] = (f16)v;
      }
}

// ---------------- 128x128 fp16 GEMM (O-proj; split-K via blockIdx.z) ----------------
template <int OUTMODE>
__global__ __launch_bounds__(256, 4) void gemm128(
    const f16* __restrict__ A, const f16* __restrict__ B,
    const float* __restrict__ bias, void* __restrict__ Cptr, int K, int aq1,
    int aq3, int ldb, long cp1, long cp3) {
  const int kz = blockIdx.z;
  A += (long)kz * (K >> 8) * (long)aq3;
  B += (long)kz * K;
  __shared__ f16 As[4][128 * 32];
  __shared__ f16 Bs[4][128 * 32];
  const int tid = threadIdx.x;
  const int m0 = blockIdx.y * 128;
  const int n0 = blockIdx.x * 128;
  const int lane = tid & 63, wid = tid >> 6;
  const int l15 = lane & 15, lg = lane >> 4;
  const int wm = (wid >> 1) * 64, wn = (wid & 1) * 64;

  f32x4 acc[4][4] = {};

  auto stage = [&](int buf, int kt) {
    int k0 = kt * 32;
#pragma unroll
    for (int r = 0; r < 2; ++r) {
      int flat = r * 4096 + tid * 16;
      int row = flat >> 6;
      int kk = k0 + ((flat & 63) >> 1);
      int m = m0 + row;
      gload16(A + (long)(m >> 8) * aq1 + (long)(m & 255) * 256 +
                  (long)(kk >> 8) * aq3 + (kk & 255),
              (char*)(&As[buf][0]) + flat);
      int n = n0 + row;
      gload16(B + (long)n * ldb + kk, (char*)(&Bs[buf][0]) + flat);
    }
  };

  auto compute = [&](int t) {
    const f16* as = &As[t & 3][0];
    const f16* bs = &Bs[t & 3][0];
    f16x8 af[4], bf[4];
#pragma unroll
    for (int i = 0; i < 4; ++i)
      af[i] = *(const f16x8*)(as + (wm + i * 16 + l15) * 32 + lg * 8);
#pragma unroll
    for (int j = 0; j < 4; ++j)
      bf[j] = *(const f16x8*)(bs + (wn + j * 16 + l15) * 32 + lg * 8);
#pragma unroll
    for (int i = 0; i < 4; ++i)
#pragma unroll
      for (int j = 0; j < 4; ++j)
        acc[i][j] =
            __builtin_amdgcn_mfma_f32_16x16x32_f16(af[i], bf[j], acc[i][j], 0, 0, 0);
  };

  const int T = K >> 5;
  stage(0, 0);
  stage(1, 1);
  for (int t = 0; t < T - 2; ++t) {
    stage((t + 2) & 3, t + 2);
    VMW(8);
    barrier_fenced();
    compute(t);
  }
  VMW(4);
  barrier_fenced();
  compute(T - 2);
  VMW(0);
  barrier_fenced();
  compute(T - 1);

#pragma unroll
  for (int i = 0; i < 4; ++i) {
#pragma unroll
    for (int j = 0; j < 4; ++j) {
#pragma unroll
      for (int jj = 0; jj < 4; ++jj) {
        int m = m0 + wm + i * 16 + lg * 4 + jj;
        int n = n0 + wn + j * 16 + l15;
        float v = acc[i][j][jj];
        if (OUTMODE != 3) v += (OUTMODE == 1) ? bias[m] : bias[n];
        long off = (long)(m >> 8) * cp1 + (long)(m & 255) * 256 +
                   (long)(n >> 8) * cp3 + (n & 255);
        if (OUTMODE == 3)
          ((float*)Cptr)[off + (long)kz * 65536] = v;
        else if (OUTMODE == 2)
          ((float*)Cptr)[off] = v;
        else
          ((f16*)Cptr)[off] = (f16)v;
      }
    }
  }
}

// sum 2 split-K partials + bias -> d_out (fp32)
__global__ __launch_bounds__(256) void reduce_out(const float* __restrict__ P,
                                                  const float* __restrict__ bo,
                                                  float* __restrict__ out) {
  int i = (blockIdx.x * 256 + threadIdx.x) * 4;
  int n = i & 255, tok = (i >> 8) & 255, bc = i >> 16;
  long b = (long)bc * 524288 + (long)tok * 256 + n;
  float4 a0 = *(const float4*)(P + b);
  float4 a1 = *(const float4*)(P + b + 65536);
  float4 bb = *(const float4*)(bo + n);
  float4 r = {a0.x + a1.x + bb.x, a0.y + a1.y + bb.y, a0.z + a1.z + bb.z,
              a0.w + a1.w + bb.w};
  *(float4*)(out + i) = r;
}

// ---------------- fused attention v5: q-tile 128, 4 waves, 2 blocks/CU ----------------
// 256 thr; wave w owns q rows [w*32, w*32+32) of this block's 128-row q-tile.
// LDS 80 KiB: phase A overlays {Qt 2x8KB @0, Kt 2x16KB @16384} inside the
// P region [128 rows][256 cols] f16 swizzled @0..65536; V 2x8KB @65536.
// Grid (2 qt, 8 h, 64 bc) = 1024 blocks -> 2 co-resident blocks/CU.
__global__ __launch_bounds__(256, 2) void attn_fused5(const f16* __restrict__ QK,
                                                      const f16* __restrict__ Vw,
                                                      f16* __restrict__ Ow) {
  __shared__ __align__(16) char smem[81920];
  const int tid = threadIdx.x;
  const int lane = tid & 63, wid = tid >> 6;  // 4 waves
  const int l15 = lane & 15, lg = lane >> 4;
  const int qt = blockIdx.x, h = blockIdx.y, bc = blockIdx.z;
  const long base = (long)bc * 1048576 + (long)h * 65536;
  const long obase = base + (long)qt * 128 * 256;
  const f16* Qh = QK + obase;                 // this block's 128 q rows
  const f16* Kh = QK + base + 524288;
  const f16* Vh = Vw + (long)bc * 524288 + (long)h * 65536;  // V^T [d][kq]
  const int w32 = wid * 32;

  // Q tile [128 rows][32 k] 8KB; source-side swizzle, LDS dest linear
  auto stageQ = [&](int t) {
#pragma unroll
    for (int r = 0; r < 2; ++r) {
      int flat = r * 4096 + tid * 16;
      int row = flat >> 6;
      int kk = t * 32 + (((flat ^ (((row >> 1) & 3) << 4)) & 63) >> 1);
      gload16(Qh + (long)row * 256 + kk, smem + (t & 1) * 8192 + flat);
    }
  };
  // K tile [256 rows][32 k] 16KB
  auto stageK = [&](int t) {
#pragma unroll
    for (int r = 0; r < 4; ++r) {
      int flat = r * 4096 + tid * 16;
      int row = flat >> 6;
      int kk = t * 32 + (((flat ^ (((row >> 1) & 3) << 4)) & 63) >> 1);
      gload16(Kh + (long)row * 256 + kk, smem + 16384 + (t & 1) * 16384 + flat);
    }
  };
  // V sub-tile st = kvtile*2 + dh: [128 d][32 kv] 8KB @65536 + (st&1)*8192
  auto stageV = [&](int st) {
#pragma unroll
    for (int r = 0; r < 2; ++r) {
      int flat = r * 4096 + tid * 16;
      int row = flat >> 6;
      int kk = (st >> 1) * 32 + (((flat ^ (((row >> 1) & 3) << 4)) & 63) >> 1);
      gload16(Vh + (long)((st & 1) * 128 + row) * 256 + kk,
              smem + 65536 + (st & 1) * 8192 + flat);
    }
  };
  auto ldQ = [&](int t, int row, int koff) -> f16x8 {
    return *(const f16x8*)(smem + (t & 1) * 8192 + row * 64 +
                           (koff ^ (((row >> 1) & 3) << 4)));
  };
  auto ldK = [&](int t, int row, int koff) -> f16x8 {
    return *(const f16x8*)(smem + 16384 + (t & 1) * 16384 + row * 64 +
                           (koff ^ (((row >> 1) & 3) << 4)));
  };
  auto ldV = [&](int st, int row, int koff) -> f16x8 {
    return *(const f16x8*)(smem + 65536 + (st & 1) * 8192 + row * 64 +
                           (koff ^ (((row >> 1) & 3) << 4)));
  };

  // ---------- phase A: S = Q K^T (per wave: 32 q rows x 256 kv) ----------
  f32x4 acc[2][16] = {};
  stageQ(0);
  stageK(0);
#pragma unroll
  for (int t = 0; t < 8; ++t) {
    VMW(0);            // tile t landed (wave-local)
    barrier_fenced();  // tile t visible to all waves; buf (t+1)&1 free
    if (t < 7) {
      stageQ(t + 1);
      stageK(t + 1);
    } else {
      stageV(0);  // prefetch V st=0; drains under softmax
    }
    f16x8 af[2];
#pragma unroll
    for (int i = 0; i < 2; ++i) af[i] = ldQ(t, w32 + i * 16 + l15, lg * 16);
    __builtin_amdgcn_s_setprio(1);
#pragma unroll
    for (int j = 0; j < 16; ++j) {
      f16x8 b = ldK(t, j * 16 + l15, lg * 16);
#pragma unroll
      for (int i = 0; i < 2; ++i)
        acc[i][j] =
            __builtin_amdgcn_mfma_f32_16x16x32_f16(af[i], b, acc[i][j], 0, 0, 0);
    }
    __builtin_amdgcn_s_setprio(0);
  }
  barrier_fenced();  // all waves' Q/K LDS reads done; P may overwrite region

  // ---------- softmax over 256 cols (rows wave-local) ----------
  const float SCL = 0.0625f * 1.44269504089f;
  float inv[2][4];
#pragma unroll
  for (int i = 0; i < 2; ++i) {
#pragma unroll
    for (int jj = 0; jj < 4; ++jj) {
      float m_ = acc[i][0][jj];
#pragma unroll
      for (int f = 1; f < 16; ++f) m_ = fmaxf(m_, acc[i][f][jj]);
#pragma unroll
      for (int off = 1; off < 16; off <<= 1) m_ = fmaxf(m_, __shfl_xor(m_, off, 64));
      float s_ = 0.f;
#pragma unroll
      for (int f = 0; f < 16; ++f) {
        float e = __builtin_exp2f((acc[i][f][jj] - m_) * SCL);
        acc[i][f][jj] = e;
        s_ += e;
      }
#pragma unroll
      for (int off = 1; off < 16; off <<= 1) s_ += __shfl_xor(s_, off, 64);
      inv[i][jj] = 1.f / s_;
    }
  }

  // write P [128 rows][256 cols] f16 @0..65536: byte = row*512 + (col*2 ^ ((row&7)<<4))
#pragma unroll
  for (int i = 0; i < 2; ++i)
#pragma unroll
    for (int f = 0; f < 16; ++f)
#pragma unroll
      for (int jj = 0; jj < 4; ++jj) {
        int row = w32 + i * 16 + lg * 4 + jj;
        int colb = (f * 16 + l15) * 2;
        *(f16*)(smem + row * 512 + (colb ^ ((row & 7) << 4))) =
            (f16)(acc[i][f][jj] * inv[i][jj]);
      }

  // ---------- phase B: O = P V over 16 V sub-tiles (distance-1, 2-buf) ----------
  f32x4 oacc[2][16] = {};
#pragma unroll
  for (int st = 0; st < 16; ++st) {
    VMW(0);            // V(st) landed
    barrier_fenced();  // visible to all waves; buf (st+1)&1 free
    if (st < 15) stageV(st + 1);
    const int t = st >> 1, dh = st & 1;
    f16x8 pf[2];
#pragma unroll
    for (int i = 0; i < 2; ++i) {
      int row = w32 + i * 16 + l15;
      pf[i] = *(const f16x8*)(smem + row * 512 +
                              ((t * 64 + lg * 16) ^ ((row & 7) << 4)));
    }
    __builtin_amdgcn_s_setprio(1);
#pragma unroll
    for (int jj = 0; jj < 8; ++jj) {
      f16x8 b = ldV(st, jj * 16 + l15, lg * 16);
      const int j = dh * 8 + jj;
#pragma unroll
      for (int i = 0; i < 2; ++i)
        oacc[i][j] =
            __builtin_amdgcn_mfma_f32_16x16x32_f16(pf[i], b, oacc[i][j], 0, 0, 0);
    }
    __builtin_amdgcn_s_setprio(0);
  }

  // write O tile into the Q slice (aliased; this block's Q reads are done)
#pragma unroll
  for (int i = 0; i < 2; ++i)
#pragma unroll
    for (int f = 0; f < 16; ++f)
#pragma unroll
      for (int jj = 0; jj < 4; ++jj) {
        int q = w32 + i * 16 + lg * 4 + jj;  // local row in this q-tile
        int d = f * 16 + l15;
        Ow[obase + (long)q * 256 + d] = (f16)(oacc[i][f][jj]);
      }
}

// ---------------- launch ----------------
// ws layout (bytes):
//   xb    @ 0         8388608   fp16 x [16384][256]
//   WqT   @ 8388608   1048576   (contiguous with WkT -> fused QK B [4096][256])
//   WkT   @ 9437184   1048576
//   WvT   @ 10485760  1048576
//   WoT   @ 11534336  1048576
//   bqp   @ 12582912  8192      (contiguous with bkp -> fused bias [4096])
//   bkp   @ 12591104  8192
//   bvp   @ 12599296  8192
//   QK    @ 12607488  134217728 interleaved [bc][qk][h][q][d] f16
//            qk=0: Q (attn O overwrites in place); qk=1: K (dead after attn,
//            reused for O-proj fp32 partials)
//   VT    @ +134217728 67108864 [bc][h][d][q] f16
extern "C" void kernel_launch(void* const* d_in, const int* in_sizes, int n_in,
                              void* d_out, int out_size, void* d_ws,
                              size_t ws_size, hipStream_t stream) {
  const float* x = (const float*)d_in[0];
  const float* Wq = (const float*)d_in[1];
  const float* bq = (const float*)d_in[2];
  const float* Wk = (const float*)d_in[3];
  const float* bk = (const float*)d_in[4];
  const float* Wv = (const float*)d_in[5];
  const float* bv = (const float*)d_in[6];
  const float* Wo = (const float*)d_in[7];
  const float* bo = (const float*)d_in[8];

  char* ws = (char*)d_ws;
  f16* xb = (f16*)(ws + 0);
  f16* WqT = (f16*)(ws + 8388608);
  f16* WkT = (f16*)(ws + 9437184);
  f16* WvT = (f16*)(ws + 10485760);
  f16* WoT = (f16*)(ws + 11534336);
  float* bqp = (float*)(ws + 12582912);
  float* bkp = (float*)(ws + 12591104);
  float* bvp = (float*)(ws + 12599296);
  f16* QKws = (f16*)(ws + 12607488);
  f16* VTs = (f16*)(ws + 12607488 + 134217728L);
  float* Opart = (float*)(ws + 12607488 + 1048576);  // dead K half, per-bc 524288 f32
  if (ws_size < 12607488ull + 134217728ull + 67108864ull) return;  // ~204MB

  prep_all<<<4096, 256, 0, stream>>>(x, Wq, Wk, Wv, Wo, bq, bk, bv, xb, WqT,
                                     WkT, WvT, WoT, bqp, bkp, bvp);

  // blocks 0..1023: QK-proj (M=16384, N=4096, K=256)
  // blocks 1024..1535: V-proj swapped -> V^T (M=2048, N=16384, K=256)
  gemm_qkv<<<1536, 512, 0, stream>>>(xb, WqT, bqp, QKws, WvT, xb, bvp, VTs);

  attn_fused5<<<dim3(2, 8, 64), 256, 0, stream>>>(QKws, VTs, QKws);

  // output projection, split-K=2 (1024 each): M=16384, N=256, fp32 partials
  gemm128<3><<<dim3(2, 128, 2), 256, 0, stream>>>(QKws, WoT, nullptr, Opart,
                                                  1024, 1048576, 65536, 2048,
                                                  524288L, 0L);
  reduce_out<<<4096, 256, 0, stream>>>(Opart, bo, (float*)d_out);
}